// Round 15
// baseline (790.638 us; speedup 1.0000x reference)
//
#include <hip/hip_runtime.h>
#include <hip/hip_bf16.h>
#include <stdint.h>
#include <math.h>

// ---------------- types / helpers ----------------
typedef __attribute__((ext_vector_type(8))) short bf16x8;   // 8 bf16 in 4 VGPRs
typedef __attribute__((ext_vector_type(4))) float f32x4;

#define AS1 __attribute__((address_space(1)))
#define AS3 __attribute__((address_space(3)))

__device__ __forceinline__ ushort f2bf(float f) {
  union { float f; uint32_t u; } in; in.f = f;
  uint32_t u = in.u;
  uint32_t r = u + 0x7fffu + ((u >> 16) & 1u);   // RNE; inputs finite
  return (ushort)(r >> 16);
}
__device__ __forceinline__ float bf2f(ushort h) {
  union { uint32_t u; float f; } out; out.u = ((uint32_t)h) << 16;
  return out.f;
}

// ---------------- cast f32 -> bf16 (vectorized) ----------------
__global__ __launch_bounds__(256)
void cast_f32_bf16(const float4* __restrict__ in, ushort4* __restrict__ out, int n4) {
  int i = blockIdx.x * blockDim.x + threadIdx.x;
  int stride = gridDim.x * blockDim.x;
  for (; i < n4; i += stride) {
    float4 v = in[i];
    ushort4 o;
    o.x = f2bf(v.x); o.y = f2bf(v.y); o.z = f2bf(v.z); o.w = f2bf(v.w);
    out[i] = o;
  }
}

// ---------------- V (B,LK,D) f32 -> Vt (B,D,LK) bf16 ----------------
__global__ __launch_bounds__(256)
void transpose_cast_v(const float* __restrict__ V, ushort* __restrict__ Vt) {
  __shared__ ushort tile[32][33];                // +1 pad: no bank conflicts
  const int b  = blockIdx.z;
  const int k0 = blockIdx.x * 32;
  const int d0 = blockIdx.y * 32;
  const int tx = threadIdx.x;                    // 0..31
  const int ty = threadIdx.y;                    // 0..7
  const float* Vb = V + ((size_t)b * 1024 + k0) * 1024 + d0;
  #pragma unroll
  for (int r = 0; r < 4; ++r) {
    int k = ty * 4 + r;
    tile[k][tx] = f2bf(Vb[(size_t)k * 1024 + tx]);
  }
  __syncthreads();
  ushort* Vtb = Vt + ((size_t)b * 1024 + d0) * 1024 + k0;
  #pragma unroll
  for (int r = 0; r < 4; ++r) {
    int d = ty * 4 + r;
    Vtb[(size_t)d * 1024 + tx] = tile[tx][d];
  }
}

// ---------------- masked softmax over each (b,q) row of S (bf16 in/out) ----
__global__ __launch_bounds__(256)
void softmax_mask(const ushort* __restrict__ S, ushort* __restrict__ P,
                  const float* __restrict__ mask) {
  const int rowId = blockIdx.x;                  // 0..B*LQ-1
  const int b = rowId >> 10;                     // LQ = 1024
  const ushort4* srow = (const ushort4*)(S + (size_t)rowId * 1024);
  const float4* mrow = (const float4*)(mask + (size_t)b * 1024);
  const int t = threadIdx.x;
  const int wid = t >> 6, lane = t & 63;

  ushort4 sv = srow[t];
  float4 mv = mrow[t];
  float s[4] = {bf2f(sv.x), bf2f(sv.y), bf2f(sv.z), bf2f(sv.w)};
  float m[4] = {mv.x, mv.y, mv.z, mv.w};

  float mx = -INFINITY;
  #pragma unroll
  for (int i = 0; i < 4; ++i) if (m[i] != 0.f) mx = fmaxf(mx, s[i]);
  #pragma unroll
  for (int off = 32; off > 0; off >>= 1)
    mx = fmaxf(mx, __shfl_xor(mx, off));

  __shared__ float wred[4][2];
  if (lane == 0) wred[wid][0] = mx;
  __syncthreads();
  float M = fmaxf(fmaxf(wred[0][0], wred[1][0]), fmaxf(wred[2][0], wred[3][0]));

  float e[4]; float sum = 0.f;
  #pragma unroll
  for (int i = 0; i < 4; ++i) {
    e[i] = (m[i] != 0.f) ? __expf(s[i] - M) : 0.f;
    sum += e[i];
  }
  #pragma unroll
  for (int off = 32; off > 0; off >>= 1)
    sum += __shfl_xor(sum, off);
  if (lane == 0) wred[wid][1] = sum;
  __syncthreads();
  float Z = wred[0][1] + wred[1][1] + wred[2][1] + wred[3][1];
  float inv = (Z > 0.f) ? 1.f / Z : 0.f;

  ushort4 o;
  o.x = f2bf(e[0] * inv); o.y = f2bf(e[1] * inv);
  o.z = f2bf(e[2] * inv); o.w = f2bf(e[3] * inv);
  ((ushort4*)(P + (size_t)rowId * 1024))[t] = o;
}

// ---------------- GEMM 128x128, BK=64, 4 waves, single-buffer (r9) --------
// C = A(Mx1024,row) * Bt(1024x1024,row)^T.
// r9 base (best: 134 us/GEMM) + ONE change: __launch_bounds__(256,5) ->
// 5 blocks/CU (LDS 5x32 KiB = 160 KiB exact; VGPR 56 << 102 cap).
// r14 lesson: blocks walking K in lockstep SHARE L2 hits on K-panels
// (stagger raised FETCH 2.6x and regressed) -- keep aligned K-walk.
// Epoch model: ~2510 cyc = LDS traffic (4blk x 96KB ~ 150 B/cyc demanded
// vs ~112 achievable) + barrier-coupled latency; 5th block fills the
// latency fraction.
// + T2 swizzle (0 conflicts): byte involution y ^= (y>>3)&0x70 (rule #21).
// + T1 XCD remap (all grids here are multiples of 8).
// EPI: 0 -> outBf = bf16(acc*scale)                              (S)
//      1 -> outBf = bf16(bf2f(auxBf) + acc)                      (X = Q + PV)
//      2 -> outBf = bf16(relu(acc + bias[col]))                  (FFN1 -> h)
//      3 -> outF  = acc + bias[col] + bf2f(auxBf)                (FFN2 + residual)
template<int EPI>
__global__ __launch_bounds__(256, 5)
void gemm128(const ushort* __restrict__ A, const ushort* __restrict__ Bt,
             size_t aBatch, size_t bBatch, size_t oBatch,
             float scale,
             ushort* outBf, float* outF, const ushort* auxBf,
             const float* __restrict__ bias)
{
  constexpr int K = 1024, N = 1024, NT = 16;    // K-tiles of 64
  __shared__ ushort lsA[128 * 64];              // 16 KiB
  __shared__ ushort lsB[128 * 64];              // 16 KiB
  const int t = threadIdx.x;
  const int w = t >> 6, lane = t & 63;
  const int wr = w >> 1, wc = w & 1;            // 2 x 2 waves -> 64x64 per wave
  const int lr16 = lane & 15, kg = lane >> 4;

  // T1: XCD-aware bijective remap (nwg is a multiple of 8 for all our grids)
  const unsigned nx = gridDim.x, ny = gridDim.y;
  unsigned flat = blockIdx.x + nx * (blockIdx.y + ny * blockIdx.z);
  const unsigned nwg = nx * ny * gridDim.z;
  const unsigned cpx = nwg >> 3;
  unsigned nf = (flat & 7u) * cpx + (flat >> 3);
  const unsigned bxi = nf % nx;
  const unsigned rest = nf / nx;
  const unsigned byi = rest % ny;
  const unsigned bz = rest / ny;
  const int m0 = byi * 128, n0 = bxi * 128;

  const char* Ab = (const char*)(A + (size_t)bz * aBatch + (size_t)m0 * K);
  const char* Bb = (const char*)(Bt + (size_t)bz * bBatch + (size_t)n0 * K);

  // staging decode: 4 chunks of 16B/lane per matrix per thread (16 KiB tile).
  // lds-linear byte y = (w*4+i)*1024 + lane*16; unswizzled tile byte
  // tb = y ^ ((y>>3)&0x70); global = (tb>>7)*2048 + (tb&127) + kt*128.
  int gOff[4], lOff[4];
  #pragma unroll
  for (int i = 0; i < 4; ++i) {
    int y = (w * 4 + i) * 1024 + lane * 16;
    int tb = y ^ ((y >> 3) & 0x70);
    gOff[i] = (tb >> 7) * 2048 + (tb & 127);
    lOff[i] = (w * 4 + i) * 1024;               // wave-uniform LDS base (+lane*16 by HW)
  }

  // fragment reads (swizzled): row*128 + ((ks*4+kg)^(row&7))*16, row&7 = lr16&7
  const int sl0 = (kg ^ (lr16 & 7)) << 4;
  const int aBase = (wr * 64 + lr16) * 128 + sl0;
  const int bBase = (wc * 64 + lr16) * 128 + sl0;

  f32x4 acc[4][4];
  #pragma unroll
  for (int i = 0; i < 4; ++i)
    #pragma unroll
    for (int j = 0; j < 4; ++j)
      acc[i][j] = (f32x4){0.f, 0.f, 0.f, 0.f};

  #pragma unroll 1
  for (int kt = 0; kt < NT; ++kt) {
    // stage tile kt into the single buffer (4+4 gload_lds w=16 per thread)
    #pragma unroll
    for (int i = 0; i < 4; ++i)
      __builtin_amdgcn_global_load_lds(
        (const AS1 void*)(Ab + gOff[i] + kt * 128),
        (AS3 void*)((char*)lsA + lOff[i]), 16, 0, 0);
    #pragma unroll
    for (int i = 0; i < 4; ++i)
      __builtin_amdgcn_global_load_lds(
        (const AS1 void*)(Bb + gOff[i] + kt * 128),
        (AS3 void*)((char*)lsB + lOff[i]), 16, 0, 0);
    __syncthreads();                            // compiler: vmcnt(0) drain

    #pragma unroll
    for (int ks = 0; ks < 2; ++ks) {
      bf16x8 af[4], bfv[4];
      #pragma unroll
      for (int mi = 0; mi < 4; ++mi)
        af[mi] = *(const bf16x8*)((const char*)lsA + ((aBase + mi * 2048) ^ (ks * 64)));
      #pragma unroll
      for (int ni = 0; ni < 4; ++ni)
        bfv[ni] = *(const bf16x8*)((const char*)lsB + ((bBase + ni * 2048) ^ (ks * 64)));
      #pragma unroll
      for (int mi = 0; mi < 4; ++mi)
        #pragma unroll
        for (int ni = 0; ni < 4; ++ni)
          acc[mi][ni] = __builtin_amdgcn_mfma_f32_16x16x32_bf16(
              af[mi], bfv[ni], acc[mi][ni], 0, 0, 0);
    }
    __syncthreads();                            // reads drained before re-stage
  }

  // epilogue: C/D layout col=lane&15, row=(lane>>4)*4+j  [m89-verified]
  const int lr4 = kg * 4;
  #pragma unroll
  for (int mi = 0; mi < 4; ++mi) {
    #pragma unroll
    for (int ni = 0; ni < 4; ++ni) {
      int row = m0 + wr * 64 + mi * 16 + lr4;
      int col = n0 + wc * 64 + ni * 16 + lr16;
      size_t o = (size_t)bz * oBatch + (size_t)row * N + col;
      f32x4 v = acc[mi][ni];
      #pragma unroll
      for (int j = 0; j < 4; ++j) {
        size_t oo = o + (size_t)j * N;
        float x = v[j];
        if (EPI == 0) {
          outBf[oo] = f2bf(x * scale);
        } else if (EPI == 1) {
          outBf[oo] = f2bf(bf2f(auxBf[oo]) + x);
        } else if (EPI == 2) {
          float h = x + bias[col];
          h = h > 0.f ? h : 0.f;
          outBf[oo] = f2bf(h);
        } else {
          outF[oo] = x + bias[col] + bf2f(auxBf[oo]);
        }
      }
    }
  }
}

// ---------------- launch ----------------
extern "C" void kernel_launch(void* const* d_in, const int* in_sizes, int n_in,
                              void* d_out, int out_size, void* d_ws, size_t ws_size,
                              hipStream_t stream) {
  (void)in_sizes; (void)n_in; (void)out_size; (void)ws_size;
  const float* Q  = (const float*)d_in[0];
  const float* Km = (const float*)d_in[1];
  const float* V  = (const float*)d_in[2];
  const float* Vm = (const float*)d_in[3];
  const float* W1 = (const float*)d_in[4];
  const float* b1 = (const float*)d_in[5];
  const float* W2 = (const float*)d_in[6];
  const float* b2 = (const float*)d_in[7];
  float* out = (float*)d_out;

  const int LQ = 1024, LK = 1024, D = 1024;
  const size_t NQ = (size_t)32 * LQ * D;            // 33.5M elems

  // workspace layout (MiB offsets): Qb 0..64, Kb/hb 64..128, Vt 128..192,
  // Sb 192..256, P 256..320, Xb 320..384, W1b 384..386, W2b 386..388
  char* ws = (char*)d_ws;
  ushort* Qb  = (ushort*)(ws);
  ushort* Kb  = (ushort*)(ws + ((size_t)64 << 20));
  ushort* hb  = Kb;                                  // reuse (Kb dead after S-GEMM)
  ushort* Vt  = (ushort*)(ws + ((size_t)128 << 20));
  ushort* Sb  = (ushort*)(ws + ((size_t)192 << 20));
  ushort* P   = (ushort*)(ws + ((size_t)256 << 20));
  ushort* Xb  = (ushort*)(ws + ((size_t)320 << 20));
  ushort* W1b = (ushort*)(ws + ((size_t)384 << 20));
  ushort* W2b = (ushort*)(ws + ((size_t)386 << 20));

  const float inv_scale = 1.0f / (sqrtf(1024.0f) + 1e-8f);

  cast_f32_bf16<<<2048, 256, 0, stream>>>((const float4*)Q,  (ushort4*)Qb, (int)(NQ / 4));
  cast_f32_bf16<<<2048, 256, 0, stream>>>((const float4*)Km, (ushort4*)Kb, (int)(NQ / 4));
  cast_f32_bf16<<<256, 256, 0, stream>>>((const float4*)W1, (ushort4*)W1b, (1024 * 1024) / 4);
  cast_f32_bf16<<<256, 256, 0, stream>>>((const float4*)W2, (ushort4*)W2b, (1024 * 1024) / 4);
  transpose_cast_v<<<dim3(32, 32, 32), dim3(32, 8), 0, stream>>>(V, Vt);

  // Sb = bf16((Qb @ Kb^T) * inv_scale), batched over 32
  gemm128<0><<<dim3(8, 8, 32), 256, 0, stream>>>(
      Qb, Kb,
      (size_t)LQ * D, (size_t)LK * D, (size_t)LQ * LK,
      inv_scale, Sb, nullptr, nullptr, nullptr);

  softmax_mask<<<32768, 256, 0, stream>>>(Sb, P, Vm);

  // Xb = bf16(Qb + P @ V)
  gemm128<1><<<dim3(8, 8, 32), 256, 0, stream>>>(
      P, Vt,
      (size_t)LQ * LK, (size_t)D * LK, (size_t)LQ * D,
      1.f, Xb, nullptr, Qb, nullptr);

  // hb = bf16(relu(Xb @ W1^T + b1)); M = 32768 folded into blockIdx.y
  gemm128<2><<<dim3(8, 256, 1), 256, 0, stream>>>(
      Xb, W1b, 0, 0, 0,
      1.f, hb, nullptr, nullptr, b1);

  // out = hb @ W2^T + b2 + Xb
  gemm128<3><<<dim3(8, 256, 1), 256, 0, stream>>>(
      hb, W2b, 0, 0, 0,
      1.f, nullptr, out, Xb, b2);
}

// Round 16
// 537.049 us; speedup vs baseline: 1.4722x; 1.4722x over previous
//
#include <hip/hip_runtime.h>
#include <hip/hip_bf16.h>
#include <stdint.h>
#include <math.h>

// ---------------- types / helpers ----------------
typedef __attribute__((ext_vector_type(8))) short bf16x8;   // 8 bf16 in 4 VGPRs
typedef __attribute__((ext_vector_type(4))) float f32x4;

#define AS1 __attribute__((address_space(1)))
#define AS3 __attribute__((address_space(3)))

__device__ __forceinline__ ushort f2bf(float f) {
  union { float f; uint32_t u; } in; in.f = f;
  uint32_t u = in.u;
  uint32_t r = u + 0x7fffu + ((u >> 16) & 1u);   // RNE; inputs finite
  return (ushort)(r >> 16);
}
__device__ __forceinline__ float bf2f(ushort h) {
  union { uint32_t u; float f; } out; out.u = ((uint32_t)h) << 16;
  return out.f;
}

// ---------------- cast f32 -> bf16 (vectorized) ----------------
__global__ __launch_bounds__(256)
void cast_f32_bf16(const float4* __restrict__ in, ushort4* __restrict__ out, int n4) {
  int i = blockIdx.x * blockDim.x + threadIdx.x;
  int stride = gridDim.x * blockDim.x;
  for (; i < n4; i += stride) {
    float4 v = in[i];
    ushort4 o;
    o.x = f2bf(v.x); o.y = f2bf(v.y); o.z = f2bf(v.z); o.w = f2bf(v.w);
    out[i] = o;
  }
}

// ---------------- V (B,LK,D) f32 -> Vt (B,D,LK) bf16 ----------------
__global__ __launch_bounds__(256)
void transpose_cast_v(const float* __restrict__ V, ushort* __restrict__ Vt) {
  __shared__ ushort tile[32][33];                // +1 pad: no bank conflicts
  const int b  = blockIdx.z;
  const int k0 = blockIdx.x * 32;
  const int d0 = blockIdx.y * 32;
  const int tx = threadIdx.x;                    // 0..31
  const int ty = threadIdx.y;                    // 0..7
  const float* Vb = V + ((size_t)b * 1024 + k0) * 1024 + d0;
  #pragma unroll
  for (int r = 0; r < 4; ++r) {
    int k = ty * 4 + r;
    tile[k][tx] = f2bf(Vb[(size_t)k * 1024 + tx]);
  }
  __syncthreads();
  ushort* Vtb = Vt + ((size_t)b * 1024 + d0) * 1024 + k0;
  #pragma unroll
  for (int r = 0; r < 4; ++r) {
    int d = ty * 4 + r;
    Vtb[(size_t)d * 1024 + tx] = tile[tx][d];
  }
}

// ---------------- masked softmax over each (b,q) row of S (bf16 in/out) ----
__global__ __launch_bounds__(256)
void softmax_mask(const ushort* __restrict__ S, ushort* __restrict__ P,
                  const float* __restrict__ mask) {
  const int rowId = blockIdx.x;                  // 0..B*LQ-1
  const int b = rowId >> 10;                     // LQ = 1024
  const ushort4* srow = (const ushort4*)(S + (size_t)rowId * 1024);
  const float4* mrow = (const float4*)(mask + (size_t)b * 1024);
  const int t = threadIdx.x;
  const int wid = t >> 6, lane = t & 63;

  ushort4 sv = srow[t];
  float4 mv = mrow[t];
  float s[4] = {bf2f(sv.x), bf2f(sv.y), bf2f(sv.z), bf2f(sv.w)};
  float m[4] = {mv.x, mv.y, mv.z, mv.w};

  float mx = -INFINITY;
  #pragma unroll
  for (int i = 0; i < 4; ++i) if (m[i] != 0.f) mx = fmaxf(mx, s[i]);
  #pragma unroll
  for (int off = 32; off > 0; off >>= 1)
    mx = fmaxf(mx, __shfl_xor(mx, off));

  __shared__ float wred[4][2];
  if (lane == 0) wred[wid][0] = mx;
  __syncthreads();
  float M = fmaxf(fmaxf(wred[0][0], wred[1][0]), fmaxf(wred[2][0], wred[3][0]));

  float e[4]; float sum = 0.f;
  #pragma unroll
  for (int i = 0; i < 4; ++i) {
    e[i] = (m[i] != 0.f) ? __expf(s[i] - M) : 0.f;
    sum += e[i];
  }
  #pragma unroll
  for (int off = 32; off > 0; off >>= 1)
    sum += __shfl_xor(sum, off);
  if (lane == 0) wred[wid][1] = sum;
  __syncthreads();
  float Z = wred[0][1] + wred[1][1] + wred[2][1] + wred[3][1];
  float inv = (Z > 0.f) ? 1.f / Z : 0.f;

  ushort4 o;
  o.x = f2bf(e[0] * inv); o.y = f2bf(e[1] * inv);
  o.z = f2bf(e[2] * inv); o.w = f2bf(e[3] * inv);
  ((ushort4*)(P + (size_t)rowId * 1024))[t] = o;
}

// ---------------- GEMM 128x128, BK=64, 4 waves, single-buffer (r9) --------
// C = A(Mx1024,row) * Bt(1024x1024,row)^T.
// r9 exact revert — the measured optimum of this engine's search:
// - 32 KiB LDS single-buffer, 2 barriers/K-tile, no inline asm (compiler
//   emits vmcnt/lgkm drains at __syncthreads).
// - __launch_bounds__(256,4): unified VGPR+AGPR budget = 56+64 = 120 <= 128
//   (512/4).  5 blocks (cap 102) spills acc -> r15 regression; 3 blocks
//   (128 KiB LDS structures) serializes -> r3-r8 plateau.  4 is optimal.
// - lockstep K-walk across co-resident blocks shares L2 K-panels (r14:
//   stagger raised FETCH 2.6x and regressed).
// + T2 swizzle (0 conflicts): byte involution y ^= (y>>3)&0x70 (rule #21:
//   linear gload_lds dest + inverse-swizzled global src + swizzled ds_read).
// + T1 XCD remap (all grids here are multiples of 8).
// EPI: 0 -> outBf = bf16(acc*scale)                              (S)
//      1 -> outBf = bf16(bf2f(auxBf) + acc)                      (X = Q + PV)
//      2 -> outBf = bf16(relu(acc + bias[col]))                  (FFN1 -> h)
//      3 -> outF  = acc + bias[col] + bf2f(auxBf)                (FFN2 + residual)
template<int EPI>
__global__ __launch_bounds__(256, 4)
void gemm128(const ushort* __restrict__ A, const ushort* __restrict__ Bt,
             size_t aBatch, size_t bBatch, size_t oBatch,
             float scale,
             ushort* outBf, float* outF, const ushort* auxBf,
             const float* __restrict__ bias)
{
  constexpr int K = 1024, N = 1024, NT = 16;    // K-tiles of 64
  __shared__ ushort lsA[128 * 64];              // 16 KiB
  __shared__ ushort lsB[128 * 64];              // 16 KiB
  const int t = threadIdx.x;
  const int w = t >> 6, lane = t & 63;
  const int wr = w >> 1, wc = w & 1;            // 2 x 2 waves -> 64x64 per wave
  const int lr16 = lane & 15, kg = lane >> 4;

  // T1: XCD-aware bijective remap (nwg is a multiple of 8 for all our grids)
  const unsigned nx = gridDim.x, ny = gridDim.y;
  unsigned flat = blockIdx.x + nx * (blockIdx.y + ny * blockIdx.z);
  const unsigned nwg = nx * ny * gridDim.z;
  const unsigned cpx = nwg >> 3;
  unsigned nf = (flat & 7u) * cpx + (flat >> 3);
  const unsigned bxi = nf % nx;
  const unsigned rest = nf / nx;
  const unsigned byi = rest % ny;
  const unsigned bz = rest / ny;
  const int m0 = byi * 128, n0 = bxi * 128;

  const char* Ab = (const char*)(A + (size_t)bz * aBatch + (size_t)m0 * K);
  const char* Bb = (const char*)(Bt + (size_t)bz * bBatch + (size_t)n0 * K);

  // staging decode: 4 chunks of 16B/lane per matrix per thread (16 KiB tile).
  // lds-linear byte y = (w*4+i)*1024 + lane*16; unswizzled tile byte
  // tb = y ^ ((y>>3)&0x70); global = (tb>>7)*2048 + (tb&127) + kt*128.
  int gOff[4], lOff[4];
  #pragma unroll
  for (int i = 0; i < 4; ++i) {
    int y = (w * 4 + i) * 1024 + lane * 16;
    int tb = y ^ ((y >> 3) & 0x70);
    gOff[i] = (tb >> 7) * 2048 + (tb & 127);
    lOff[i] = (w * 4 + i) * 1024;               // wave-uniform LDS base (+lane*16 by HW)
  }

  // fragment reads (swizzled): row*128 + ((ks*4+kg)^(row&7))*16, row&7 = lr16&7
  const int sl0 = (kg ^ (lr16 & 7)) << 4;
  const int aBase = (wr * 64 + lr16) * 128 + sl0;
  const int bBase = (wc * 64 + lr16) * 128 + sl0;

  f32x4 acc[4][4];
  #pragma unroll
  for (int i = 0; i < 4; ++i)
    #pragma unroll
    for (int j = 0; j < 4; ++j)
      acc[i][j] = (f32x4){0.f, 0.f, 0.f, 0.f};

  #pragma unroll 1
  for (int kt = 0; kt < NT; ++kt) {
    // stage tile kt into the single buffer (4+4 gload_lds w=16 per thread)
    #pragma unroll
    for (int i = 0; i < 4; ++i)
      __builtin_amdgcn_global_load_lds(
        (const AS1 void*)(Ab + gOff[i] + kt * 128),
        (AS3 void*)((char*)lsA + lOff[i]), 16, 0, 0);
    #pragma unroll
    for (int i = 0; i < 4; ++i)
      __builtin_amdgcn_global_load_lds(
        (const AS1 void*)(Bb + gOff[i] + kt * 128),
        (AS3 void*)((char*)lsB + lOff[i]), 16, 0, 0);
    __syncthreads();                            // compiler: vmcnt(0) drain

    #pragma unroll
    for (int ks = 0; ks < 2; ++ks) {
      bf16x8 af[4], bfv[4];
      #pragma unroll
      for (int mi = 0; mi < 4; ++mi)
        af[mi] = *(const bf16x8*)((const char*)lsA + ((aBase + mi * 2048) ^ (ks * 64)));
      #pragma unroll
      for (int ni = 0; ni < 4; ++ni)
        bfv[ni] = *(const bf16x8*)((const char*)lsB + ((bBase + ni * 2048) ^ (ks * 64)));
      #pragma unroll
      for (int mi = 0; mi < 4; ++mi)
        #pragma unroll
        for (int ni = 0; ni < 4; ++ni)
          acc[mi][ni] = __builtin_amdgcn_mfma_f32_16x16x32_bf16(
              af[mi], bfv[ni], acc[mi][ni], 0, 0, 0);
    }
    __syncthreads();                            // reads drained before re-stage
  }

  // epilogue: C/D layout col=lane&15, row=(lane>>4)*4+j  [m89-verified]
  const int lr4 = kg * 4;
  #pragma unroll
  for (int mi = 0; mi < 4; ++mi) {
    #pragma unroll
    for (int ni = 0; ni < 4; ++ni) {
      int row = m0 + wr * 64 + mi * 16 + lr4;
      int col = n0 + wc * 64 + ni * 16 + lr16;
      size_t o = (size_t)bz * oBatch + (size_t)row * N + col;
      f32x4 v = acc[mi][ni];
      #pragma unroll
      for (int j = 0; j < 4; ++j) {
        size_t oo = o + (size_t)j * N;
        float x = v[j];
        if (EPI == 0) {
          outBf[oo] = f2bf(x * scale);
        } else if (EPI == 1) {
          outBf[oo] = f2bf(bf2f(auxBf[oo]) + x);
        } else if (EPI == 2) {
          float h = x + bias[col];
          h = h > 0.f ? h : 0.f;
          outBf[oo] = f2bf(h);
        } else {
          outF[oo] = x + bias[col] + bf2f(auxBf[oo]);
        }
      }
    }
  }
}

// ---------------- launch ----------------
extern "C" void kernel_launch(void* const* d_in, const int* in_sizes, int n_in,
                              void* d_out, int out_size, void* d_ws, size_t ws_size,
                              hipStream_t stream) {
  (void)in_sizes; (void)n_in; (void)out_size; (void)ws_size;
  const float* Q  = (const float*)d_in[0];
  const float* Km = (const float*)d_in[1];
  const float* V  = (const float*)d_in[2];
  const float* Vm = (const float*)d_in[3];
  const float* W1 = (const float*)d_in[4];
  const float* b1 = (const float*)d_in[5];
  const float* W2 = (const float*)d_in[6];
  const float* b2 = (const float*)d_in[7];
  float* out = (float*)d_out;

  const int LQ = 1024, LK = 1024, D = 1024;
  const size_t NQ = (size_t)32 * LQ * D;            // 33.5M elems

  // workspace layout (MiB offsets): Qb 0..64, Kb/hb 64..128, Vt 128..192,
  // Sb 192..256, P 256..320, Xb 320..384, W1b 384..386, W2b 386..388
  char* ws = (char*)d_ws;
  ushort* Qb  = (ushort*)(ws);
  ushort* Kb  = (ushort*)(ws + ((size_t)64 << 20));
  ushort* hb  = Kb;                                  // reuse (Kb dead after S-GEMM)
  ushort* Vt  = (ushort*)(ws + ((size_t)128 << 20));
  ushort* Sb  = (ushort*)(ws + ((size_t)192 << 20));
  ushort* P   = (ushort*)(ws + ((size_t)256 << 20));
  ushort* Xb  = (ushort*)(ws + ((size_t)320 << 20));
  ushort* W1b = (ushort*)(ws + ((size_t)384 << 20));
  ushort* W2b = (ushort*)(ws + ((size_t)386 << 20));

  const float inv_scale = 1.0f / (sqrtf(1024.0f) + 1e-8f);

  cast_f32_bf16<<<2048, 256, 0, stream>>>((const float4*)Q,  (ushort4*)Qb, (int)(NQ / 4));
  cast_f32_bf16<<<2048, 256, 0, stream>>>((const float4*)Km, (ushort4*)Kb, (int)(NQ / 4));
  cast_f32_bf16<<<256, 256, 0, stream>>>((const float4*)W1, (ushort4*)W1b, (1024 * 1024) / 4);
  cast_f32_bf16<<<256, 256, 0, stream>>>((const float4*)W2, (ushort4*)W2b, (1024 * 1024) / 4);
  transpose_cast_v<<<dim3(32, 32, 32), dim3(32, 8), 0, stream>>>(V, Vt);

  // Sb = bf16((Qb @ Kb^T) * inv_scale), batched over 32
  gemm128<0><<<dim3(8, 8, 32), 256, 0, stream>>>(
      Qb, Kb,
      (size_t)LQ * D, (size_t)LK * D, (size_t)LQ * LK,
      inv_scale, Sb, nullptr, nullptr, nullptr);

  softmax_mask<<<32768, 256, 0, stream>>>(Sb, P, Vm);

  // Xb = bf16(Qb + P @ V)
  gemm128<1><<<dim3(8, 8, 32), 256, 0, stream>>>(
      P, Vt,
      (size_t)LQ * LK, (size_t)D * LK, (size_t)LQ * D,
      1.f, Xb, nullptr, Qb, nullptr);

  // hb = bf16(relu(Xb @ W1^T + b1)); M = 32768 folded into blockIdx.y
  gemm128<2><<<dim3(8, 256, 1), 256, 0, stream>>>(
      Xb, W1b, 0, 0, 0,
      1.f, hb, nullptr, nullptr, b1);

  // out = hb @ W2^T + b2 + Xb
  gemm128<3><<<dim3(8, 256, 1), 256, 0, stream>>>(
      hb, W2b, 0, 0, 0,
      1.f, nullptr, out, Xb, b2);
}